// Round 1
// baseline (150.230 us; speedup 1.0000x reference)
//
#include <hip/hip_runtime.h>
#include <math.h>

#define KDIM 256
#define NITER 50

__global__ __launch_bounds__(256) void cacis_main(
    const float* __restrict__ scores,
    const int* __restrict__ targets,
    const float* __restrict__ C,
    float* __restrict__ lossB)
{
    const int b = blockIdx.x;
    const int tid = threadIdx.x;
    const int lane = tid & 63;
    const int wave = tid >> 6;
    const float* Cb = C + (size_t)b * KDIM * KDIM;
    const float4* C4 = (const float4*)Cb;

    __shared__ float4 sf4[KDIM/4];   // f = 0.5*scores, as float4 for conflict-free reads
    __shared__ float red[KDIM];
    __shared__ float rs[KDIM];
    __shared__ float bc[4];
    __shared__ float wmin[4];
    __shared__ int   widx[4];
    __shared__ int   sIdx[64];
    __shared__ float sLog[64];
    __shared__ int   sCount;

    const float* sf = (const float*)sf4;
    ((float*)sf4)[tid] = 0.5f * scores[b*KDIM + tid];
    __syncthreads();

    // ---------- pass 1: sum(C), trace(C), min over (i,j) of f_i+f_j+C_ij ----------
    float psum = 0.f, ptrace = 0.f, pmin = INFINITY;
    for (int row = wave; row < KDIM; row += 4) {
        float4 c4 = C4[row*(KDIM/4) + lane];     // wave reads full row coalesced
        float frow = sf[row];                     // wave-uniform -> LDS broadcast
        float4 fj = sf4[lane];
        psum += (c4.x + c4.y) + (c4.z + c4.w);
        pmin = fminf(pmin, fminf(fminf(frow+fj.x+c4.x, frow+fj.y+c4.y),
                                 fminf(frow+fj.z+c4.z, frow+fj.w+c4.w)));
        if ((row >> 2) == lane) {                 // diagonal element lives in this lane's float4
            int rr = row & 3;
            ptrace += (rr==0) ? c4.x : (rr==1) ? c4.y : (rr==2) ? c4.z : c4.w;
        }
    }
    red[tid] = psum; __syncthreads();
    for (int s = 128; s > 0; s >>= 1) { if (tid < s) red[tid] += red[tid+s]; __syncthreads(); }
    if (tid == 0) bc[0] = red[0];
    __syncthreads();
    red[tid] = ptrace; __syncthreads();
    for (int s = 128; s > 0; s >>= 1) { if (tid < s) red[tid] += red[tid+s]; __syncthreads(); }
    if (tid == 0) bc[1] = red[0];
    __syncthreads();
    red[tid] = pmin; __syncthreads();
    for (int s = 128; s > 0; s >>= 1) { if (tid < s) red[tid] = fminf(red[tid], red[tid+s]); __syncthreads(); }
    if (tid == 0) bc[2] = red[0];
    __syncthreads();

    const float sumAll = bc[0], trace = bc[1], minv = bc[2];
    const float offmean = (sumAll - trace) / (float)(KDIM*KDIM - KDIM);
    const float eps = fmaxf(offmean, 1e-8f);
    const float inv_eps = 1.0f / eps;
    // shift = -minv/eps ; logM_ij = (minv - (f_i+f_j+C_ij))/eps  (always <= 0)

    // ---------- pass 2: rowsum_i of M (one wave per row, shfl-reduce) ----------
    for (int row = wave; row < KDIM; row += 4) {
        float4 c4 = C4[row*(KDIM/4) + lane];
        float frow = sf[row];
        float4 fj = sf4[lane];
        float p = __expf((minv - (frow+fj.x+c4.x)) * inv_eps)
                + __expf((minv - (frow+fj.y+c4.y)) * inv_eps)
                + __expf((minv - (frow+fj.z+c4.z)) * inv_eps)
                + __expf((minv - (frow+fj.w+c4.w)) * inv_eps);
        for (int off = 32; off > 0; off >>= 1) p += __shfl_xor(p, off);
        if (lane == 0) rs[row] = p;
    }
    __syncthreads();

    // ---------- Frank-Wolfe: incremental grad, one M-column per iteration ----------
    const float fi = sf[tid];
    float g = rs[tid] * (2.0f / (float)KDIM);   // grad0 = (2/K) * rowsum
    float a = 1.0f / (float)KDIM;
    for (int it = 0; it < NITER; ++it) {
        // block argmin with lowest-index tiebreak (matches jnp.argmin)
        float v = g; int vi = tid;
        for (int off = 32; off > 0; off >>= 1) {
            float ov = __shfl_xor(v, off);
            int  ovi = __shfl_xor(vi, off);
            if (ov < v || (ov == v && ovi < vi)) { v = ov; vi = ovi; }
        }
        if (lane == 0) { wmin[wave] = v; widx[wave] = vi; }
        __syncthreads();
        float bv = wmin[0]; int bi = widx[0];
        #pragma unroll
        for (int w = 1; w < 4; ++w) {
            float wv = wmin[w]; int wi = widx[w];
            if (wv < bv || (wv == bv && wi < bi)) { bv = wv; bi = wi; }
        }
        const int idx = bi;
        const float gamma = 2.0f / ((float)it + 2.0f);   // it=0 -> gamma=1 exactly
        const float fidx = sf[idx];
        const float c = Cb[tid*KDIM + idx];              // column gather
        const float mcol = __expf((minv - (fi + fidx + c)) * inv_eps);
        g = (1.0f - gamma)*g + 2.0f*gamma*mcol;
        a = (1.0f - gamma)*a + ((tid == idx) ? gamma : 0.0f);
        __syncthreads();   // protect wmin/widx reuse next iteration
    }

    // ---------- collect support S = {i : alpha_i > 0}, |S| <= 50 ----------
    red[tid] = a;
    rs[tid]  = (a > 0.f) ? logf(a) : -INFINITY;
    __syncthreads();
    if (tid == 0) {
        int c = 0;
        for (int i = 0; i < KDIM; ++i)
            if (red[i] > 0.f) { sIdx[c] = i; sLog[c] = rs[i]; ++c; }
        sCount = c;
    }
    __syncthreads();
    const int count = sCount;

    // ---------- logsumexp over support pairs (online max+sum) ----------
    float m = -INFINITY, ss = 0.f;
    const int total = count * count;
    for (int p = tid; p < total; p += KDIM) {
        int ii = p / count;
        int jj = p - ii * count;
        int i = sIdx[ii], j = sIdx[jj];
        float cij = Cb[i*KDIM + j];
        float lm = (minv - (sf[i] + sf[j] + cij)) * inv_eps;
        float t = sLog[ii] + sLog[jj] + lm;
        if (t > m) { ss = ss * __expf(m - t) + 1.0f; m = t; }
        else       { ss += __expf(t - m); }
    }
    __syncthreads();   // red/rs free for reuse
    red[tid] = m; rs[tid] = ss;
    __syncthreads();
    for (int s = 128; s > 0; s >>= 1) {
        if (tid < s) {
            float m1 = red[tid],   s1 = rs[tid];
            float m2 = red[tid+s], s2 = rs[tid+s];
            if (s2 > 0.f) {
                if (s1 <= 0.f)    { red[tid] = m2; rs[tid] = s2; }
                else if (m2 > m1) { red[tid] = m2; rs[tid] = s1*__expf(m1-m2) + s2; }
                else              { rs[tid] = s1 + s2*__expf(m2-m1); }
            }
        }
        __syncthreads();
    }
    if (tid == 0) {
        float logval = red[0] + logf(rs[0]);
        float shift = -minv * inv_eps;
        float conjugate = -eps * (logval + shift);
        float fy = scores[b*KDIM + targets[b]];
        lossB[b] = conjugate - fy;
    }
}

__global__ __launch_bounds__(512) void cacis_reduce(const float* __restrict__ lossB,
                                                    float* __restrict__ out, int B)
{
    __shared__ float red[512];
    int t = threadIdx.x;
    red[t] = (t < B) ? lossB[t] : 0.f;
    __syncthreads();
    for (int s = 256; s > 0; s >>= 1) { if (t < s) red[t] += red[t+s]; __syncthreads(); }
    if (t == 0) out[0] = red[0] / (float)B;
}

extern "C" void kernel_launch(void* const* d_in, const int* in_sizes, int n_in,
                              void* d_out, int out_size, void* d_ws, size_t ws_size,
                              hipStream_t stream) {
    const float* scores  = (const float*)d_in[0];
    const int*   targets = (const int*)d_in[1];
    const float* C       = (const float*)d_in[2];
    float* out   = (float*)d_out;
    float* lossPerBatch = (float*)d_ws;
    const int B = in_sizes[1];   // 512

    cacis_main<<<B, KDIM, 0, stream>>>(scores, targets, C, lossPerBatch);
    cacis_reduce<<<1, 512, 0, stream>>>(lossPerBatch, out, B);
}

// Round 2
// 121.406 us; speedup vs baseline: 1.2374x; 1.2374x over previous
//
#include <hip/hip_runtime.h>
#include <math.h>

#define KDIM 256
#define NITER 50

// ws layout (floats):
// [0,2048)      psum per (b,chunk)
// [2048,4096)   ptrace
// [4096,6144)   pmin
// [6144,8192)   rsval (chunk-local min of rowsum(M))
// [8192,10240)  rsidx (int)
// [10240,10752) lossB

__global__ __launch_bounds__(256) void k1_partials(
    const float* __restrict__ scores, const float* __restrict__ C,
    float* __restrict__ psum_o, float* __restrict__ ptrace_o, float* __restrict__ pmin_o)
{
    const int blk = blockIdx.x;
    const int b = blk >> 2, chunk = blk & 3;
    const int tid = threadIdx.x, lane = tid & 63, wave = tid >> 6;
    const float4* C4 = (const float4*)(C + (size_t)b * KDIM * KDIM);

    __shared__ float4 sf4[KDIM/4];
    __shared__ float redS[256], redT[256], redM[256];
    const float* sf = (const float*)sf4;
    ((float*)sf4)[tid] = 0.5f * scores[b*KDIM + tid];
    __syncthreads();

    const int row0 = chunk * 64;
    float psum = 0.f, ptrace = 0.f, pmin = INFINITY;
    #pragma unroll
    for (int rr = 0; rr < 16; ++rr) {
        const int row = row0 + wave + rr*4;
        float4 c4 = C4[row*(KDIM/4) + lane];
        float frow = sf[row];
        float4 fj = sf4[lane];
        psum += (c4.x + c4.y) + (c4.z + c4.w);
        pmin = fminf(pmin, fminf(fminf(frow+fj.x+c4.x, frow+fj.y+c4.y),
                                 fminf(frow+fj.z+c4.z, frow+fj.w+c4.w)));
        if ((row >> 2) == lane) {
            int r2 = row & 3;
            ptrace += (r2==0) ? c4.x : (r2==1) ? c4.y : (r2==2) ? c4.z : c4.w;
        }
    }
    redS[tid] = psum; redT[tid] = ptrace; redM[tid] = pmin;
    __syncthreads();
    for (int s = 128; s > 0; s >>= 1) {
        if (tid < s) {
            redS[tid] += redS[tid+s];
            redT[tid] += redT[tid+s];
            redM[tid]  = fminf(redM[tid], redM[tid+s]);
        }
        __syncthreads();
    }
    if (tid == 0) { psum_o[blk] = redS[0]; ptrace_o[blk] = redT[0]; pmin_o[blk] = redM[0]; }
}

__global__ __launch_bounds__(256) void k2_grad0(
    const float* __restrict__ scores, const float* __restrict__ C,
    const float* __restrict__ psum_i, const float* __restrict__ ptrace_i, const float* __restrict__ pmin_i,
    float* __restrict__ rsval_o, int* __restrict__ rsidx_o)
{
    const int blk = blockIdx.x;
    const int b = blk >> 2, chunk = blk & 3;
    const int tid = threadIdx.x, lane = tid & 63, wave = tid >> 6;
    const float4* C4 = (const float4*)(C + (size_t)b * KDIM * KDIM);

    __shared__ float4 sf4[KDIM/4];
    __shared__ float rs64[64];
    const float* sf = (const float*)sf4;
    ((float*)sf4)[tid] = 0.5f * scores[b*KDIM + tid];
    __syncthreads();

    float sum = 0.f, tr = 0.f, mn = INFINITY;
    #pragma unroll
    for (int c2 = 0; c2 < 4; ++c2) {
        sum += psum_i[b*4 + c2];
        tr  += ptrace_i[b*4 + c2];
        mn   = fminf(mn, pmin_i[b*4 + c2]);
    }
    const float eps = fmaxf((sum - tr) / (float)(KDIM*KDIM - KDIM), 1e-8f);
    const float inv_eps = 1.0f / eps;
    const float minv = mn;

    const int row0 = chunk * 64;
    for (int rr = wave; rr < 64; rr += 4) {
        const int row = row0 + rr;
        float4 c4 = C4[row*(KDIM/4) + lane];
        float frow = sf[row];
        float4 fj = sf4[lane];
        float p = __expf((minv - (frow+fj.x+c4.x)) * inv_eps)
                + __expf((minv - (frow+fj.y+c4.y)) * inv_eps)
                + __expf((minv - (frow+fj.z+c4.z)) * inv_eps)
                + __expf((minv - (frow+fj.w+c4.w)) * inv_eps);
        for (int off = 32; off > 0; off >>= 1) p += __shfl_xor(p, off);
        if (lane == 0) rs64[rr] = p;
    }
    __syncthreads();
    if (wave == 0) {
        float v = rs64[lane]; int vi = row0 + lane;
        for (int off = 32; off > 0; off >>= 1) {
            float ov = __shfl_xor(v, off);
            int  ovi = __shfl_xor(vi, off);
            if (ov < v || (ov == v && ovi < vi)) { v = ov; vi = ovi; }
        }
        if (lane == 0) { rsval_o[blk] = v; rsidx_o[blk] = vi; }
    }
}

__global__ __launch_bounds__(256) void k3_fw(
    const float* __restrict__ scores, const int* __restrict__ targets,
    const float* __restrict__ C,
    const float* __restrict__ psum_i, const float* __restrict__ ptrace_i, const float* __restrict__ pmin_i,
    const float* __restrict__ rsval_i, const int* __restrict__ rsidx_i,
    float* __restrict__ lossB)
{
    const int b = blockIdx.x;
    const int tid = threadIdx.x, lane = tid & 63, wave = tid >> 6;
    const float* Cb = C + (size_t)b * KDIM * KDIM;

    __shared__ float4 sf4[KDIM/4];
    __shared__ float red[KDIM];
    __shared__ float rs[KDIM];
    __shared__ float wmin[4];
    __shared__ int   widx[4];
    __shared__ int   wcnt[4];
    __shared__ int   sIdx[64];
    __shared__ float sLog[64];

    const float* sf = (const float*)sf4;
    ((float*)sf4)[tid] = 0.5f * scores[b*KDIM + tid];
    __syncthreads();

    // eps, minv from partials
    float sum = 0.f, tr = 0.f, mn = INFINITY;
    #pragma unroll
    for (int c2 = 0; c2 < 4; ++c2) {
        sum += psum_i[b*4 + c2];
        tr  += ptrace_i[b*4 + c2];
        mn   = fminf(mn, pmin_i[b*4 + c2]);
    }
    const float eps = fmaxf((sum - tr) / (float)(KDIM*KDIM - KDIM), 1e-8f);
    const float inv_eps = 1.0f / eps;
    const float minv = mn;

    // idx0 = argmin of grad0 (chunk results are index-ordered, '<' keeps lowest idx)
    float bv = INFINITY; int idx0 = 0;
    #pragma unroll
    for (int c2 = 0; c2 < 4; ++c2) {
        float v = rsval_i[b*4 + c2];
        int  vi = rsidx_i[b*4 + c2];
        if (v < bv) { bv = v; idx0 = vi; }
    }

    // FW: it=0 done analytically (gamma=1 -> alpha = e_idx0, g = 2*M[:,idx0])
    const float fi = sf[tid];
    float a = (tid == idx0) ? 1.0f : 0.0f;
    {
        const float c = Cb[tid*KDIM + idx0];
        float dummy; (void)dummy;
        a = a; // keep
    }
    float g;
    {
        const float c = Cb[tid*KDIM + idx0];
        g = 2.0f * __expf((minv - (fi + sf[idx0] + c)) * inv_eps);
    }

    for (int it = 1; it < NITER; ++it) {
        float v = g; int vi = tid;
        for (int off = 32; off > 0; off >>= 1) {
            float ov = __shfl_xor(v, off);
            int  ovi = __shfl_xor(vi, off);
            if (ov < v || (ov == v && ovi < vi)) { v = ov; vi = ovi; }
        }
        if (lane == 0) { wmin[wave] = v; widx[wave] = vi; }
        __syncthreads();
        float cbv = wmin[0]; int cbi = widx[0];
        #pragma unroll
        for (int w = 1; w < 4; ++w) {
            float wv = wmin[w]; int wi = widx[w];
            if (wv < cbv || (wv == cbv && wi < cbi)) { cbv = wv; cbi = wi; }
        }
        const int idx = cbi;
        const float gamma = 2.0f / ((float)it + 2.0f);
        const float fidx = sf[idx];
        const float c = Cb[tid*KDIM + idx];
        const float mcol = __expf((minv - (fi + fidx + c)) * inv_eps);
        g = (1.0f - gamma)*g + 2.0f*gamma*mcol;
        a = (1.0f - gamma)*a + ((tid == idx) ? gamma : 0.0f);
        __syncthreads();
    }

    // support collection via ballot compaction (<= 50 entries, tid-ordered)
    unsigned long long mask = __ballot(a > 0.f);
    if (lane == 0) wcnt[wave] = __popcll(mask);
    __syncthreads();
    int off0 = 0;
    for (int w = 0; w < wave; ++w) off0 += wcnt[w];
    const int count = wcnt[0] + wcnt[1] + wcnt[2] + wcnt[3];
    if (a > 0.f) {
        int pos = off0 + __popcll(mask & ((1ull << lane) - 1ull));
        sIdx[pos] = tid;
        sLog[pos] = logf(a);
    }
    __syncthreads();

    // logsumexp over support pairs (online max+sum)
    float m = -INFINITY, ss = 0.f;
    const int total = count * count;
    for (int p = tid; p < total; p += KDIM) {
        int ii = p / count;
        int jj = p - ii * count;
        int i = sIdx[ii], j = sIdx[jj];
        float cij = Cb[i*KDIM + j];
        float lm = (minv - (sf[i] + sf[j] + cij)) * inv_eps;
        float t = sLog[ii] + sLog[jj] + lm;
        if (t > m) { ss = ss * __expf(m - t) + 1.0f; m = t; }
        else       { ss += __expf(t - m); }
    }
    red[tid] = m; rs[tid] = ss;
    __syncthreads();
    for (int s = 128; s > 0; s >>= 1) {
        if (tid < s) {
            float m1 = red[tid],   s1 = rs[tid];
            float m2 = red[tid+s], s2 = rs[tid+s];
            if (s2 > 0.f) {
                if (s1 <= 0.f)    { red[tid] = m2; rs[tid] = s2; }
                else if (m2 > m1) { red[tid] = m2; rs[tid] = s1*__expf(m1-m2) + s2; }
                else              { rs[tid] = s1 + s2*__expf(m2-m1); }
            }
        }
        __syncthreads();
    }
    if (tid == 0) {
        float logval = red[0] + logf(rs[0]);
        float shift = -minv * inv_eps;
        float conjugate = -eps * (logval + shift);
        float fy = scores[b*KDIM + targets[b]];
        lossB[b] = conjugate - fy;
    }
}

__global__ __launch_bounds__(512) void cacis_reduce(const float* __restrict__ lossB,
                                                    float* __restrict__ out, int B)
{
    __shared__ float red[512];
    int t = threadIdx.x;
    red[t] = (t < B) ? lossB[t] : 0.f;
    __syncthreads();
    for (int s = 256; s > 0; s >>= 1) { if (t < s) red[t] += red[t+s]; __syncthreads(); }
    if (t == 0) out[0] = red[0] / (float)B;
}

extern "C" void kernel_launch(void* const* d_in, const int* in_sizes, int n_in,
                              void* d_out, int out_size, void* d_ws, size_t ws_size,
                              hipStream_t stream) {
    const float* scores  = (const float*)d_in[0];
    const int*   targets = (const int*)d_in[1];
    const float* C       = (const float*)d_in[2];
    float* out = (float*)d_out;
    const int B = in_sizes[1];   // 512

    float* ws     = (float*)d_ws;
    float* psum   = ws;
    float* ptrace = ws + 2048;
    float* pmin   = ws + 4096;
    float* rsval  = ws + 6144;
    int*   rsidx  = (int*)(ws + 8192);
    float* lossB  = ws + 10240;

    k1_partials<<<B*4, 256, 0, stream>>>(scores, C, psum, ptrace, pmin);
    k2_grad0   <<<B*4, 256, 0, stream>>>(scores, C, psum, ptrace, pmin, rsval, rsidx);
    k3_fw      <<<B,   256, 0, stream>>>(scores, targets, C, psum, ptrace, pmin, rsval, rsidx, lossB);
    cacis_reduce<<<1, 512, 0, stream>>>(lossB, out, B);
}

// Round 3
// 112.126 us; speedup vs baseline: 1.3398x; 1.0828x over previous
//
#include <hip/hip_runtime.h>
#include <math.h>

#define KDIM 256
#define NITER 50

// ws layout (floats):
// [0,2048)      psum per (b,chunk)
// [2048,4096)   ptrace
// [4096,6144)   pmin
// [6144,8192)   rsval (chunk-local min of rowsum(M))
// [8192,10240)  rsidx (int)
// [10240,10752) lossB

__global__ __launch_bounds__(256) void k1_partials(
    const float* __restrict__ scores, const float* __restrict__ C,
    float* __restrict__ psum_o, float* __restrict__ ptrace_o, float* __restrict__ pmin_o)
{
    const int blk = blockIdx.x;
    const int b = blk >> 2, chunk = blk & 3;
    const int tid = threadIdx.x, lane = tid & 63, wave = tid >> 6;
    const float4* C4 = (const float4*)(C + (size_t)b * KDIM * KDIM);

    __shared__ float4 sf4[KDIM/4];
    __shared__ float redS[256], redT[256], redM[256];
    const float* sf = (const float*)sf4;
    ((float*)sf4)[tid] = 0.5f * scores[b*KDIM + tid];
    __syncthreads();

    const int row0 = chunk * 64;
    float psum = 0.f, ptrace = 0.f, pmin = INFINITY;
    #pragma unroll
    for (int rr = 0; rr < 16; ++rr) {
        const int row = row0 + wave + rr*4;
        float4 c4 = C4[row*(KDIM/4) + lane];
        float frow = sf[row];
        float4 fj = sf4[lane];
        psum += (c4.x + c4.y) + (c4.z + c4.w);
        pmin = fminf(pmin, fminf(fminf(frow+fj.x+c4.x, frow+fj.y+c4.y),
                                 fminf(frow+fj.z+c4.z, frow+fj.w+c4.w)));
        if ((row >> 2) == lane) {
            int r2 = row & 3;
            ptrace += (r2==0) ? c4.x : (r2==1) ? c4.y : (r2==2) ? c4.z : c4.w;
        }
    }
    redS[tid] = psum; redT[tid] = ptrace; redM[tid] = pmin;
    __syncthreads();
    for (int s = 128; s > 0; s >>= 1) {
        if (tid < s) {
            redS[tid] += redS[tid+s];
            redT[tid] += redT[tid+s];
            redM[tid]  = fminf(redM[tid], redM[tid+s]);
        }
        __syncthreads();
    }
    if (tid == 0) { psum_o[blk] = redS[0]; ptrace_o[blk] = redT[0]; pmin_o[blk] = redM[0]; }
}

__global__ __launch_bounds__(256) void k2_grad0(
    const float* __restrict__ scores, const float* __restrict__ C,
    const float* __restrict__ psum_i, const float* __restrict__ ptrace_i, const float* __restrict__ pmin_i,
    float* __restrict__ rsval_o, int* __restrict__ rsidx_o)
{
    const int blk = blockIdx.x;
    const int b = blk >> 2, chunk = blk & 3;
    const int tid = threadIdx.x, lane = tid & 63, wave = tid >> 6;
    const float4* C4 = (const float4*)(C + (size_t)b * KDIM * KDIM);

    __shared__ float4 sf4[KDIM/4];
    __shared__ float rs64[64];
    const float* sf = (const float*)sf4;
    ((float*)sf4)[tid] = 0.5f * scores[b*KDIM + tid];
    __syncthreads();

    float sum = 0.f, tr = 0.f, mn = INFINITY;
    #pragma unroll
    for (int c2 = 0; c2 < 4; ++c2) {
        sum += psum_i[b*4 + c2];
        tr  += ptrace_i[b*4 + c2];
        mn   = fminf(mn, pmin_i[b*4 + c2]);
    }
    const float eps = fmaxf((sum - tr) / (float)(KDIM*KDIM - KDIM), 1e-8f);
    const float inv_eps = 1.0f / eps;
    const float minv = mn;

    const int row0 = chunk * 64;
    for (int rr = wave; rr < 64; rr += 4) {
        const int row = row0 + rr;
        float4 c4 = C4[row*(KDIM/4) + lane];
        float frow = sf[row];
        float4 fj = sf4[lane];
        float p = __expf((minv - (frow+fj.x+c4.x)) * inv_eps)
                + __expf((minv - (frow+fj.y+c4.y)) * inv_eps)
                + __expf((minv - (frow+fj.z+c4.z)) * inv_eps)
                + __expf((minv - (frow+fj.w+c4.w)) * inv_eps);
        for (int off = 32; off > 0; off >>= 1) p += __shfl_xor(p, off);
        if (lane == 0) rs64[rr] = p;
    }
    __syncthreads();
    if (wave == 0) {
        float v = rs64[lane]; int vi = row0 + lane;
        for (int off = 32; off > 0; off >>= 1) {
            float ov = __shfl_xor(v, off);
            int  ovi = __shfl_xor(vi, off);
            if (ov < v || (ov == v && ovi < vi)) { v = ov; vi = ovi; }
        }
        if (lane == 0) { rsval_o[blk] = v; rsidx_o[blk] = vi; }
    }
}

__global__ __launch_bounds__(256) void k3_fw(
    const float* __restrict__ scores, const int* __restrict__ targets,
    const float* __restrict__ C,
    const float* __restrict__ psum_i, const float* __restrict__ ptrace_i, const float* __restrict__ pmin_i,
    const float* __restrict__ rsval_i, const int* __restrict__ rsidx_i,
    float* __restrict__ lossB)
{
    const int b = blockIdx.x;
    const int tid = threadIdx.x, lane = tid & 63, wave = tid >> 6;
    const float* Cb = C + (size_t)b * KDIM * KDIM;

    __shared__ float4 sf4[KDIM/4];
    __shared__ float aAll[KDIM];
    __shared__ float wm[4], wsm[4];
    __shared__ int   wcnt[4];
    __shared__ int   sIdx[64];
    __shared__ float sLog[64];

    const float* sf = (const float*)sf4;
    ((float*)sf4)[tid] = 0.5f * scores[b*KDIM + tid];
    __syncthreads();

    // eps, minv from partials (all threads, redundant)
    float sum = 0.f, tr = 0.f, mn = INFINITY;
    #pragma unroll
    for (int c2 = 0; c2 < 4; ++c2) {
        sum += psum_i[b*4 + c2];
        tr  += ptrace_i[b*4 + c2];
        mn   = fminf(mn, pmin_i[b*4 + c2]);
    }
    const float eps = fmaxf((sum - tr) / (float)(KDIM*KDIM - KDIM), 1e-8f);
    const float inv_eps = 1.0f / eps;
    const float minv = mn;

    // idx0 = argmin of grad0 (chunk results index-ordered; strict < keeps lowest)
    float bv = INFINITY; int idx0 = 0;
    #pragma unroll
    for (int c2 = 0; c2 < 4; ++c2) {
        float v = rsval_i[b*4 + c2];
        int  vi = rsidx_i[b*4 + c2];
        if (v < bv) { bv = v; idx0 = vi; }
    }

    // ---------- FW on a single wave: lane owns rows {lane, lane+64, lane+128, lane+192} ----------
    if (wave == 0) {
        const float f0 = sf[lane], f1 = sf[lane+64], f2 = sf[lane+128], f3 = sf[lane+192];
        const float* r0 = Cb + (size_t)lane*KDIM;
        const float* r1 = r0 + 64*KDIM;
        const float* r2 = r0 + 128*KDIM;
        const float* r3 = r0 + 192*KDIM;

        float fidx = sf[idx0];
        float g0 = 2.0f * __expf((minv - (f0 + fidx + r0[idx0])) * inv_eps);
        float g1 = 2.0f * __expf((minv - (f1 + fidx + r1[idx0])) * inv_eps);
        float g2 = 2.0f * __expf((minv - (f2 + fidx + r2[idx0])) * inv_eps);
        float g3 = 2.0f * __expf((minv - (f3 + fidx + r3[idx0])) * inv_eps);
        float a0 = (lane     == idx0) ? 1.0f : 0.0f;
        float a1 = (lane+64  == idx0) ? 1.0f : 0.0f;
        float a2 = (lane+128 == idx0) ? 1.0f : 0.0f;
        float a3 = (lane+192 == idx0) ? 1.0f : 0.0f;

        for (int it = 1; it < NITER; ++it) {
            // per-lane min over 4 rows (rows ascending with w; strict < keeps lowest)
            float v = g0; int vi = lane;
            if (g1 < v) { v = g1; vi = lane+64; }
            if (g2 < v) { v = g2; vi = lane+128; }
            if (g3 < v) { v = g3; vi = lane+192; }
            // in-wave butterfly argmin, lowest-index tiebreak
            #pragma unroll
            for (int off = 32; off > 0; off >>= 1) {
                float ov = __shfl_xor(v, off);
                int  ovi = __shfl_xor(vi, off);
                if (ov < v || (ov == v && ovi < vi)) { v = ov; vi = ovi; }
            }
            const int idx = vi;
            const float gamma = 2.0f / ((float)it + 2.0f);
            const float omg = 1.0f - gamma;
            fidx = sf[idx];
            const float c0 = r0[idx], c1 = r1[idx], c2_ = r2[idx], c3 = r3[idx];
            g0 = omg*g0 + 2.0f*gamma*__expf((minv - (f0 + fidx + c0)) * inv_eps);
            g1 = omg*g1 + 2.0f*gamma*__expf((minv - (f1 + fidx + c1)) * inv_eps);
            g2 = omg*g2 + 2.0f*gamma*__expf((minv - (f2 + fidx + c2_)) * inv_eps);
            g3 = omg*g3 + 2.0f*gamma*__expf((minv - (f3 + fidx + c3)) * inv_eps);
            a0 = omg*a0 + ((lane     == idx) ? gamma : 0.0f);
            a1 = omg*a1 + ((lane+64  == idx) ? gamma : 0.0f);
            a2 = omg*a2 + ((lane+128 == idx) ? gamma : 0.0f);
            a3 = omg*a3 + ((lane+192 == idx) ? gamma : 0.0f);
        }
        aAll[lane]     = a0;
        aAll[lane+64]  = a1;
        aAll[lane+128] = a2;
        aAll[lane+192] = a3;
    }
    __syncthreads();

    const float a = aAll[tid];

    // support collection via ballot compaction (<= 50 entries, tid-ordered)
    unsigned long long mask = __ballot(a > 0.f);
    if (lane == 0) wcnt[wave] = __popcll(mask);
    __syncthreads();
    int off0 = 0;
    for (int w = 0; w < wave; ++w) off0 += wcnt[w];
    const int count = wcnt[0] + wcnt[1] + wcnt[2] + wcnt[3];
    if (a > 0.f) {
        int pos = off0 + __popcll(mask & ((1ull << lane) - 1ull));
        sIdx[pos] = tid;
        sLog[pos] = logf(a);
    }
    __syncthreads();

    // logsumexp over support pairs (online max+sum), in-wave reduce
    float m = -INFINITY, ss = 0.f;
    const int total = count * count;
    for (int p = tid; p < total; p += KDIM) {
        int ii = p / count;
        int jj = p - ii * count;
        int i = sIdx[ii], j = sIdx[jj];
        float cij = Cb[i*KDIM + j];
        float lm = (minv - (sf[i] + sf[j] + cij)) * inv_eps;
        float t = sLog[ii] + sLog[jj] + lm;
        if (t > m) { ss = ss * __expf(m - t) + 1.0f; m = t; }
        else       { ss += __expf(t - m); }
    }
    #pragma unroll
    for (int off = 32; off > 0; off >>= 1) {
        float om = __shfl_xor(m, off);
        float os = __shfl_xor(ss, off);
        if (os > 0.f) {
            if (ss <= 0.f)   { m = om; ss = os; }
            else if (om > m) { ss = ss*__expf(m-om) + os; m = om; }
            else             { ss += os*__expf(om-m); }
        }
    }
    if (lane == 0) { wm[wave] = m; wsm[wave] = ss; }
    __syncthreads();
    if (tid == 0) {
        float M = wm[0], S = wsm[0];
        #pragma unroll
        for (int w = 1; w < 4; ++w) {
            float om = wm[w], os = wsm[w];
            if (os > 0.f) {
                if (S <= 0.f)    { M = om; S = os; }
                else if (om > M) { S = S*__expf(M-om) + os; M = om; }
                else             { S += os*__expf(om-M); }
            }
        }
        float logval = M + logf(S);
        float shift = -minv * inv_eps;
        float conjugate = -eps * (logval + shift);
        float fy = scores[b*KDIM + targets[b]];
        lossB[b] = conjugate - fy;
    }
}

__global__ __launch_bounds__(512) void cacis_reduce(const float* __restrict__ lossB,
                                                    float* __restrict__ out, int B)
{
    __shared__ float red[512];
    int t = threadIdx.x;
    red[t] = (t < B) ? lossB[t] : 0.f;
    __syncthreads();
    for (int s = 256; s > 0; s >>= 1) { if (t < s) red[t] += red[t+s]; __syncthreads(); }
    if (t == 0) out[0] = red[0] / (float)B;
}

extern "C" void kernel_launch(void* const* d_in, const int* in_sizes, int n_in,
                              void* d_out, int out_size, void* d_ws, size_t ws_size,
                              hipStream_t stream) {
    const float* scores  = (const float*)d_in[0];
    const int*   targets = (const int*)d_in[1];
    const float* C       = (const float*)d_in[2];
    float* out = (float*)d_out;
    const int B = in_sizes[1];   // 512

    float* ws     = (float*)d_ws;
    float* psum   = ws;
    float* ptrace = ws + 2048;
    float* pmin   = ws + 4096;
    float* rsval  = ws + 6144;
    int*   rsidx  = (int*)(ws + 8192);
    float* lossB  = ws + 10240;

    k1_partials<<<B*4, 256, 0, stream>>>(scores, C, psum, ptrace, pmin);
    k2_grad0   <<<B*4, 256, 0, stream>>>(scores, C, psum, ptrace, pmin, rsval, rsidx);
    k3_fw      <<<B,   256, 0, stream>>>(scores, targets, C, psum, ptrace, pmin, rsval, rsidx, lossB);
    cacis_reduce<<<1, 512, 0, stream>>>(lossB, out, B);
}